// Round 4
// baseline (932.622 us; speedup 1.0000x reference)
//
#include <hip/hip_runtime.h>
#include <hip/hip_bf16.h>

#define B_   128
#define S_   512
#define H_   128
#define G_   512   // 4*H
#define EMB_ 128
#define NL_  9
#define CPW_ 2     // chains per workgroup

typedef __attribute__((ext_vector_type(8))) short bf16x8;
typedef __attribute__((ext_vector_type(4))) float f32x4;

__device__ __forceinline__ float bfbits2f(short s) {
    unsigned int u = ((unsigned int)(unsigned short)s) << 16;
    return __builtin_bit_cast(float, u);
}
// f32 -> bf16 bits, round-to-nearest-even
__device__ __forceinline__ short f2bf(float f) {
    unsigned int u = __builtin_bit_cast(unsigned int, f);
    u += 0x7FFFu + ((u >> 16) & 1u);
    return (short)(u >> 16);
}
__device__ __forceinline__ float sigm(float x) {
    return __builtin_amdgcn_rcpf(1.f + exp2f(-1.4426950408889634f * x));
}
__device__ __forceinline__ float tanh_(float x) {
    return 1.f - 2.f * __builtin_amdgcn_rcpf(1.f + exp2f(2.8853900817779268f * x));
}

// ---------------------------------------------------------------------------
// Fused LSTM + emissions. 128 wgs (64 per direction), 2 chains each, 512 thr.
// All global float data is f32; bf16 only for MFMA fragments (in-kernel cast).
// LDS A-buffer in MFMA A-fragment order: ldsA[chunk(=k/8)][row(16)], 8 bf16.
//   chunks 0..15 = x_t (EMB=128), chunks 16..31 = h (H=128).
// ---------------------------------------------------------------------------
__global__ __launch_bounds__(512, 1)
void lstm_em_kernel(const int* __restrict__ seq, const float* __restrict__ emb,
                    const float* __restrict__ w_ih_f, const float* __restrict__ w_hh_f,
                    const float* __restrict__ b_ih_f, const float* __restrict__ b_hh_f,
                    const float* __restrict__ w_ih_b, const float* __restrict__ w_hh_b,
                    const float* __restrict__ b_ih_b, const float* __restrict__ b_hh_b,
                    const float* __restrict__ w_out,
                    float* __restrict__ em_f, float* __restrict__ em_b)
{
    __shared__ bf16x8 ldsA[32 * 16];        // 8 KB
    __shared__ float  gatesL[CPW_ * G_];    // 4 KB, [chain][col]
    __shared__ float  bsum[G_];             // 2 KB

    const int tid  = threadIdx.x;
    const int wv   = tid >> 6;
    const int n16  = tid & 15;
    const int quad = (tid & 63) >> 4;
    const int dir  = blockIdx.x >> 6;
    const int brow0 = (blockIdx.x & 63) * CPW_;

    const float* wih = dir ? w_ih_b : w_ih_f;
    const float* whh = dir ? w_hh_b : w_hh_f;
    const float* bih = dir ? b_ih_b : b_ih_f;
    const float* bhh = dir ? b_hh_b : b_hh_f;
    float* emdir = dir ? em_b : em_f;

    // B fragments: wave wv owns gate columns [wv*64, wv*64+64). f32 -> bf16.
    bf16x8 bfrag[4][8];
    const int nb = wv * 64 + n16;
#pragma unroll
    for (int nt = 0; nt < 4; nt++) {
        int n = nb + nt * 16;
#pragma unroll
        for (int ks = 0; ks < 8; ks++) {
            const float* p = (ks < 4) ? (wih + n * EMB_ + ks * 32 + quad * 8)
                                      : (whh + n * H_ + (ks - 4) * 32 + quad * 8);
            bf16x8 fr;
#pragma unroll
            for (int j = 0; j < 8; j++) fr[j] = f2bf(p[j]);
            bfrag[nt][ks] = fr;
        }
    }

    // emission assignment: threads 256..399, groups of 8 lanes per (chain,label)
    const int eidx = tid - 256;
    const int eg = eidx >> 3, esub = eidx & 7;
    const bool edo = (tid >= 256) && (eg < 2 * NL_);
    const int ec = edo ? (eg / NL_) : 0;
    const int el = edo ? (eg % NL_) : 0;
    float wem[16];
    if (edo) {
#pragma unroll
        for (int k = 0; k < 16; k++)
            wem[k] = w_out[el * 256 + dir * 128 + esub * 16 + k];
    }

    bsum[tid] = bih[tid] + bhh[tid];
    { bf16x8 z = {0,0,0,0,0,0,0,0}; ldsA[tid] = z; }

    float cst = 0.f;
    const int uc = tid >> 7;     // chain for update phase (tid<256)
    const int uj = tid & 127;
    int ttprev = -1;
    __syncthreads();

    for (int t = 0; t < S_; t++) {
        const int tt = dir ? (S_ - 1 - t) : t;
        // ---- phase A: stage x_t (f32 emb -> bf16 frags); emit prev step ----
        if (tid < 16 * CPW_) {
            int row = tid >> 4, chunk = tid & 15;
            int tok = seq[(brow0 + row) * S_ + tt];
            const float* ep = emb + (size_t)tok * EMB_ + chunk * 8;
            float4 a = *(const float4*)ep;
            float4 b = *(const float4*)(ep + 4);
            bf16x8 fr;
            fr[0] = f2bf(a.x); fr[1] = f2bf(a.y); fr[2] = f2bf(a.z); fr[3] = f2bf(a.w);
            fr[4] = f2bf(b.x); fr[5] = f2bf(b.y); fr[6] = f2bf(b.z); fr[7] = f2bf(b.w);
            ldsA[chunk * 16 + row] = fr;
        } else if (edo && ttprev >= 0) {
            bf16x8 h0 = ldsA[(16 + esub * 2) * 16 + ec];
            bf16x8 h1 = ldsA[(17 + esub * 2) * 16 + ec];
            float d = 0.f;
#pragma unroll
            for (int k = 0; k < 8; k++) d += bfbits2f(h0[k]) * wem[k];
#pragma unroll
            for (int k = 0; k < 8; k++) d += bfbits2f(h1[k]) * wem[8 + k];
            d += __shfl_down(d, 4, 8);
            d += __shfl_down(d, 2, 8);
            d += __shfl_down(d, 1, 8);
            if (esub == 0)
                emdir[((size_t)(brow0 + ec) * S_ + ttprev) * NL_ + el] = d;
        }
        __syncthreads();

        // ---- phase B: gates = [x|h] @ Wcat^T via MFMA ----
        bf16x8 af[8];
#pragma unroll
        for (int ks = 0; ks < 8; ks++) af[ks] = ldsA[(ks * 4 + quad) * 16 + n16];
#pragma unroll
        for (int nt = 0; nt < 4; nt++) {
            f32x4 acc = {0.f, 0.f, 0.f, 0.f};
#pragma unroll
            for (int ks = 0; ks < 8; ks++)
                acc = __builtin_amdgcn_mfma_f32_16x16x32_bf16(af[ks], bfrag[nt][ks], acc, 0, 0, 0);
            if (quad == 0) {   // D row = quad*4+reg; rows 0,1 = chains 0,1
                int col = wv * 64 + nt * 16 + n16;
                gatesL[col] = acc[0];
                gatesL[G_ + col] = acc[1];
            }
        }
        __syncthreads();

        // ---- phase C: nonlinearity + state update; h -> LDS ----
        if (tid < CPW_ * H_) {
            float ip = gatesL[uc * G_ + uj]            + bsum[uj];
            float fp = gatesL[uc * G_ + H_ + uj]       + bsum[H_ + uj];
            float gp = gatesL[uc * G_ + 2 * H_ + uj]   + bsum[2 * H_ + uj];
            float op = gatesL[uc * G_ + 3 * H_ + uj]   + bsum[3 * H_ + uj];
            cst = sigm(fp) * cst + sigm(ip) * tanh_(gp);
            float hv = sigm(op) * tanh_(cst);
            ((short*)ldsA)[((16 + (uj >> 3)) * 16 + uc) * 8 + (uj & 7)] = f2bf(hv);
        }
        ttprev = tt;
        __syncthreads();
    }

    // ---- final emission for the last step ----
    if (edo) {
        bf16x8 h0 = ldsA[(16 + esub * 2) * 16 + ec];
        bf16x8 h1 = ldsA[(17 + esub * 2) * 16 + ec];
        float d = 0.f;
#pragma unroll
        for (int k = 0; k < 8; k++) d += bfbits2f(h0[k]) * wem[k];
#pragma unroll
        for (int k = 0; k < 8; k++) d += bfbits2f(h1[k]) * wem[8 + k];
        d += __shfl_down(d, 4, 8);
        d += __shfl_down(d, 2, 8);
        d += __shfl_down(d, 1, 8);
        if (esub == 0)
            emdir[((size_t)(brow0 + ec) * S_ + ttprev) * NL_ + el] = d;
    }
}

// ---------------------------------------------------------------------------
// CRF: one wave per batch row. em(b,t,l) = em_f + em_b + b_out[l]. All f32.
// ---------------------------------------------------------------------------
__global__ __launch_bounds__(64, 4)
void crf_kernel(const int* __restrict__ seq, const int* __restrict__ lab,
                const float* __restrict__ em_f, const float* __restrict__ em_b,
                const float* __restrict__ b_out,
                const float* __restrict__ start_t, const float* __restrict__ end_t,
                const float* __restrict__ trans, float* __restrict__ partial)
{
    const int b = blockIdx.x, lane = threadIdx.x;
    const float L2E = 1.4426950408889634f, LN2 = 0.6931471805599453f;

    // ---- numerator ----
    float np = 0.f; int cnt = 0;
    for (int t = lane; t < S_; t += 64) {
        int m = (seq[b * S_ + t] != 0);
        cnt += m;
        if (t >= 1 && m) {
            int lp = lab[b * S_ + t - 1], lc = lab[b * S_ + t];
            size_t ix = ((size_t)b * S_ + t) * NL_ + lc;
            np += trans[lp * NL_ + lc] + em_f[ix] + em_b[ix] + b_out[lc];
        }
    }
#pragma unroll
    for (int off = 32; off; off >>= 1) {
        np  += __shfl_down(np, off, 64);
        cnt += __shfl_down(cnt, off, 64);
    }
    float num = 0.f;
    if (lane == 0) {
        int l0 = lab[b * S_];
        int ll = lab[b * S_ + cnt - 1];
        size_t i0 = (size_t)b * S_ * NL_ + l0;
        num = np + start_t[l0] + em_f[i0] + em_b[i0] + b_out[l0] + end_t[ll];
    }

    // ---- denominator: sequential 9-state logsumexp forward pass ----
    const int j = (lane < NL_) ? lane : (NL_ - 1);
    const float boj = b_out[j];
    float Tc[NL_];
#pragma unroll
    for (int i = 0; i < NL_; i++) Tc[i] = trans[i * NL_ + j];
    size_t ij = (size_t)b * S_ * NL_ + j;
    float sc = start_t[j] + em_f[ij] + em_b[ij] + boj;
    for (int t = 1; t < S_; t++) {
        size_t ix = ((size_t)b * S_ + t) * NL_ + j;
        float emv = em_f[ix] + em_b[ix] + boj;
        float a[NL_];
#pragma unroll
        for (int i = 0; i < NL_; i++) a[i] = __shfl(sc, i, 64) + Tc[i];
        float m = a[0];
#pragma unroll
        for (int i = 1; i < NL_; i++) m = fmaxf(m, a[i]);
        float sum = 0.f;
#pragma unroll
        for (int i = 0; i < NL_; i++) sum += exp2f((a[i] - m) * L2E);
        float nxt = emv + m + LN2 * log2f(sum);
        sc = (seq[b * S_ + t] != 0) ? nxt : sc;
    }
    float v = sc + end_t[j];
    float mm = -1e30f, av[NL_];
#pragma unroll
    for (int i = 0; i < NL_; i++) { float vi = __shfl(v, i, 64); av[i] = vi; mm = fmaxf(mm, vi); }
    float ss = 0.f;
#pragma unroll
    for (int i = 0; i < NL_; i++) ss += exp2f((av[i] - mm) * L2E);
    if (lane == 0) partial[b] = (mm + LN2 * log2f(ss)) - num;
}

__global__ __launch_bounds__(128)
void reduce_kernel(const float* __restrict__ partial, float* __restrict__ out)
{
    __shared__ float s[128];
    int tid = threadIdx.x;
    s[tid] = partial[tid];
    __syncthreads();
    for (int off = 64; off; off >>= 1) {
        if (tid < off) s[tid] += s[tid + off];
        __syncthreads();
    }
    if (tid == 0) out[0] = s[0];   // f32 scalar output
}

extern "C" void kernel_launch(void* const* d_in, const int* in_sizes, int n_in,
                              void* d_out, int out_size, void* d_ws, size_t ws_size,
                              hipStream_t stream)
{
    const int* seq = (const int*)d_in[0];
    const int* lab = (const int*)d_in[1];
    const float* emb    = (const float*)d_in[2];
    const float* w_ih_f = (const float*)d_in[3];
    const float* w_hh_f = (const float*)d_in[4];
    const float* b_ih_f = (const float*)d_in[5];
    const float* b_hh_f = (const float*)d_in[6];
    const float* w_ih_b = (const float*)d_in[7];
    const float* w_hh_b = (const float*)d_in[8];
    const float* b_ih_b = (const float*)d_in[9];
    const float* b_hh_b = (const float*)d_in[10];
    const float* w_out  = (const float*)d_in[11];
    const float* b_out  = (const float*)d_in[12];
    const float* start_t = (const float*)d_in[13];
    const float* end_t   = (const float*)d_in[14];
    const float* trans   = (const float*)d_in[15];

    char* ws = (char*)d_ws;
    const size_t em_bytes = (size_t)B_ * S_ * NL_ * sizeof(float);   // 2.36 MB
    float* em_f   = (float*)ws;
    float* em_b   = (float*)(ws + em_bytes);
    float* partial = (float*)(ws + 2 * em_bytes);                    // total ~4.72 MB

    lstm_em_kernel<<<dim3(128), dim3(512), 0, stream>>>(seq, emb,
        w_ih_f, w_hh_f, b_ih_f, b_hh_f, w_ih_b, w_hh_b, b_ih_b, b_hh_b,
        w_out, em_f, em_b);
    crf_kernel<<<dim3(B_), dim3(64), 0, stream>>>(seq, lab, em_f, em_b, b_out,
        start_t, end_t, trans, partial);
    reduce_kernel<<<dim3(1), dim3(128), 0, stream>>>(partial, (float*)d_out);
}

// Round 5
// 789.496 us; speedup vs baseline: 1.1813x; 1.1813x over previous
//
#include <hip/hip_runtime.h>
#include <hip/hip_bf16.h>

#define B_   128
#define S_   512
#define H_   128
#define G_   512   // 4*H
#define EMB_ 128
#define NL_  9
#define CPW_ 2     // chains per workgroup

typedef __attribute__((ext_vector_type(8))) short bf16x8;
typedef __attribute__((ext_vector_type(4))) float f32x4;

// padded fragment slot: chunk stride 17 (16 rows + 1 pad) kills bank aliasing
#define FRAG(c, r) ((c) * 17 + (r))

__device__ __forceinline__ float bfbits2f(short s) {
    unsigned int u = ((unsigned int)(unsigned short)s) << 16;
    return __builtin_bit_cast(float, u);
}
__device__ __forceinline__ short f2bf(float f) {
    unsigned int u = __builtin_bit_cast(unsigned int, f);
    u += 0x7FFFu + ((u >> 16) & 1u);
    return (short)(u >> 16);
}
__device__ __forceinline__ float sigm(float x) {
    return __builtin_amdgcn_rcpf(1.f + exp2f(-1.4426950408889634f * x));
}
__device__ __forceinline__ float tanh_(float x) {
    return 1.f - 2.f * __builtin_amdgcn_rcpf(1.f + exp2f(2.8853900817779268f * x));
}

// ---------------------------------------------------------------------------
// Fused LSTM + emissions. 128 wgs (64/dir), 2 chains, 512 thr (8 waves).
// ldsA chunks (padded stride 17 frags):
//   0..15  = xbuf0 (k 0..127)    16..31 = h (k 128..255)    32..47 = xbuf1
// Per step (2 barriers):
//   P1: all waves: A-frag ds_reads + 32 MFMA + gates->LDS.
//       wave 0 extra: write prefetched x_{t+1} -> xbuf[~t&1]; issue load x_{t+2}.
//       waves 1-3 extra (144 lanes): emissions for h_{t-1} from LDS h.
//   P2: threads<256: gate nonlinearity, c/h update, h -> LDS (2-way banks).
// ---------------------------------------------------------------------------
__global__ __launch_bounds__(512, 1)
void lstm_em_kernel(const int* __restrict__ seq, const float* __restrict__ emb,
                    const float* __restrict__ w_ih_f, const float* __restrict__ w_hh_f,
                    const float* __restrict__ b_ih_f, const float* __restrict__ b_hh_f,
                    const float* __restrict__ w_ih_b, const float* __restrict__ w_hh_b,
                    const float* __restrict__ b_ih_b, const float* __restrict__ b_hh_b,
                    const float* __restrict__ w_out,
                    float* __restrict__ em_f, float* __restrict__ em_b)
{
    __shared__ bf16x8 ldsA[48 * 17];        // 13056 B
    __shared__ float  gatesL[CPW_ * G_];    // 4 KB  [chain][col]
    __shared__ float  bsum[G_];             // 2 KB
    __shared__ int    ldsSeq[CPW_ * S_];    // 4 KB  [chain][t]

    const int tid  = threadIdx.x;
    const int wv   = tid >> 6;
    const int n16  = tid & 15;
    const int quad = (tid & 63) >> 4;
    const int dir  = blockIdx.x >> 6;
    const int brow0 = (blockIdx.x & 63) * CPW_;

    const float* wih = dir ? w_ih_b : w_ih_f;
    const float* whh = dir ? w_hh_b : w_hh_f;
    const float* bih = dir ? b_ih_b : b_ih_f;
    const float* bhh = dir ? b_hh_b : b_hh_f;
    float* emdir = dir ? em_b : em_f;

    // B fragments: wave wv owns gate columns [wv*64, wv*64+64). f32 -> bf16.
    bf16x8 bfrag[4][8];
    const int nb = wv * 64 + n16;
#pragma unroll
    for (int nt = 0; nt < 4; nt++) {
        int n = nb + nt * 16;
#pragma unroll
        for (int ks = 0; ks < 8; ks++) {
            const float* p = (ks < 4) ? (wih + n * EMB_ + ks * 32 + quad * 8)
                                      : (whh + n * H_ + (ks - 4) * 32 + quad * 8);
            bf16x8 fr;
#pragma unroll
            for (int j = 0; j < 8; j++) fr[j] = f2bf(p[j]);
            bfrag[nt][ks] = fr;
        }
    }

    // emission lanes: waves 1-3, groups of 8 lanes per (chain, label)
    const int eidx = tid - 64;
    const int eg = eidx >> 3, esub = eidx & 7;
    const bool edo = (tid >= 64) && (eg < 2 * NL_);
    const int ec = edo ? (eg / NL_) : 0;
    const int el = edo ? (eg % NL_) : 0;
    float wem[16];
    if (edo) {
#pragma unroll
        for (int k = 0; k < 16; k++)
            wem[k] = w_out[el * 256 + dir * 128 + esub * 16 + k];
    }

    bsum[tid] = bih[tid] + bhh[tid];
    {   // zero A region (h must start 0; garbage rows >=2 are harmless to D rows 0,1)
        bf16x8 z = {0,0,0,0,0,0,0,0};
        for (int i = tid; i < 48 * 17; i += 512) ldsA[i] = z;
    }
    // stage token rows into LDS
    ldsSeq[tid]       = seq[(brow0 + (tid >> 9))       * S_ + (tid & 511)];
    ldsSeq[tid + 512] = seq[(brow0 + ((tid+512) >> 9)) * S_ + ((tid+512) & 511)];
    __syncthreads();

    // wave 0: preload x_0 -> xbuf0, x_1 -> rx  (lane: chain = l>>5, part = l&31)
    const int xch  = (tid & 63) >> 5;
    const int part = tid & 31;
    float4 rx = {0.f, 0.f, 0.f, 0.f};
    if (wv == 0) {
        int tt0 = dir ? (S_ - 1) : 0;
        int tt1 = dir ? (S_ - 2) : 1;
        int tok0 = ldsSeq[xch * S_ + tt0];
        int tok1 = ldsSeq[xch * S_ + tt1];
        float4 r0 = *(const float4*)(emb + (size_t)tok0 * EMB_ + part * 4);
        rx        = *(const float4*)(emb + (size_t)tok1 * EMB_ + part * 4);
        short4 s0;
        s0.x = f2bf(r0.x); s0.y = f2bf(r0.y); s0.z = f2bf(r0.z); s0.w = f2bf(r0.w);
        *(short4*)((short*)ldsA + FRAG(part >> 1, xch) * 8 + (part & 1) * 4) = s0;
    }

    float cst = 0.f;
    const int uc = tid >> 7;     // update phase (tid<256)
    const int uj = tid & 127;
    __syncthreads();

    for (int t = 0; t < S_; t++) {
        const int xb = (t & 1) ? 32 : 0;     // A-chunk base for x_t
        const int wb = 32 - xb;              // write buffer for x_{t+1}

        // ---- P1 ----
        if (wv == 0) {
            // write x_{t+1} (held in rx), then issue load of x_{t+2}
            if (t < S_ - 1) {
                short4 s;
                s.x = f2bf(rx.x); s.y = f2bf(rx.y); s.z = f2bf(rx.z); s.w = f2bf(rx.w);
                *(short4*)((short*)ldsA + FRAG(wb + (part >> 1), xch) * 8 + (part & 1) * 4) = s;
            }
            if (t < S_ - 2) {
                int tt2 = dir ? (S_ - 3 - t) : (t + 2);
                int tok = ldsSeq[xch * S_ + tt2];
                rx = *(const float4*)(emb + (size_t)tok * EMB_ + part * 4);
            }
        }
        if (edo && t > 0) {      // emissions for h produced at step t-1
            int ttp = dir ? (S_ - t) : (t - 1);
            bf16x8 h0 = ldsA[FRAG(16 + esub * 2, ec)];
            bf16x8 h1 = ldsA[FRAG(17 + esub * 2, ec)];
            float d = 0.f;
#pragma unroll
            for (int k = 0; k < 8; k++) d += bfbits2f(h0[k]) * wem[k];
#pragma unroll
            for (int k = 0; k < 8; k++) d += bfbits2f(h1[k]) * wem[8 + k];
            d += __shfl_down(d, 4, 8);
            d += __shfl_down(d, 2, 8);
            d += __shfl_down(d, 1, 8);
            if (esub == 0)
                emdir[((size_t)(brow0 + ec) * S_ + ttp) * NL_ + el] = d;
        }
        {   // MFMA: gates = [x_t | h] @ Wcat^T
            bf16x8 af[8];
#pragma unroll
            for (int ks = 0; ks < 4; ks++) af[ks] = ldsA[FRAG(xb + ks * 4 + quad, n16)];
#pragma unroll
            for (int ks = 4; ks < 8; ks++) af[ks] = ldsA[FRAG(16 + (ks - 4) * 4 + quad, n16)];
#pragma unroll
            for (int nt = 0; nt < 4; nt++) {
                f32x4 acc = {0.f, 0.f, 0.f, 0.f};
#pragma unroll
                for (int ks = 0; ks < 8; ks++)
                    acc = __builtin_amdgcn_mfma_f32_16x16x32_bf16(af[ks], bfrag[nt][ks], acc, 0, 0, 0);
                if (quad == 0) {   // D row = quad*4+reg; rows 0,1 = chains 0,1
                    int col = wv * 64 + nt * 16 + n16;
                    gatesL[col] = acc[0];
                    gatesL[G_ + col] = acc[1];
                }
            }
        }
        __syncthreads();

        // ---- P2: nonlinearity + state update; h -> LDS ----
        if (tid < CPW_ * H_) {
            float ip = gatesL[uc * G_ + uj]          + bsum[uj];
            float fp = gatesL[uc * G_ + H_ + uj]     + bsum[H_ + uj];
            float gp = gatesL[uc * G_ + 2 * H_ + uj] + bsum[2 * H_ + uj];
            float op = gatesL[uc * G_ + 3 * H_ + uj] + bsum[3 * H_ + uj];
            cst = sigm(fp) * cst + sigm(ip) * tanh_(gp);
            float hv = sigm(op) * tanh_(cst);
            ((short*)ldsA)[FRAG(16 + (uj >> 3), uc) * 8 + (uj & 7)] = f2bf(hv);
        }
        __syncthreads();
    }

    // ---- final emission (h from step S-1) ----
    if (edo) {
        int ttp = dir ? 0 : (S_ - 1);
        bf16x8 h0 = ldsA[FRAG(16 + esub * 2, ec)];
        bf16x8 h1 = ldsA[FRAG(17 + esub * 2, ec)];
        float d = 0.f;
#pragma unroll
        for (int k = 0; k < 8; k++) d += bfbits2f(h0[k]) * wem[k];
#pragma unroll
        for (int k = 0; k < 8; k++) d += bfbits2f(h1[k]) * wem[8 + k];
        d += __shfl_down(d, 4, 8);
        d += __shfl_down(d, 2, 8);
        d += __shfl_down(d, 1, 8);
        if (esub == 0)
            emdir[((size_t)(brow0 + ec) * S_ + ttp) * NL_ + el] = d;
    }
}

// ---------------------------------------------------------------------------
// CRF: one wave per batch row, software-prefetched em reads.
// ---------------------------------------------------------------------------
__global__ __launch_bounds__(64, 8)
void crf_kernel(const int* __restrict__ seq, const int* __restrict__ lab,
                const float* __restrict__ em_f, const float* __restrict__ em_b,
                const float* __restrict__ b_out,
                const float* __restrict__ start_t, const float* __restrict__ end_t,
                const float* __restrict__ trans, float* __restrict__ partial)
{
    const int b = blockIdx.x, lane = threadIdx.x;
    const float L2E = 1.4426950408889634f, LN2 = 0.6931471805599453f;

    // ---- numerator ----
    float np = 0.f; int cnt = 0;
    for (int t = lane; t < S_; t += 64) {
        int m = (seq[b * S_ + t] != 0);
        cnt += m;
        if (t >= 1 && m) {
            int lp = lab[b * S_ + t - 1], lc = lab[b * S_ + t];
            size_t ix = ((size_t)b * S_ + t) * NL_ + lc;
            np += trans[lp * NL_ + lc] + em_f[ix] + em_b[ix] + b_out[lc];
        }
    }
#pragma unroll
    for (int off = 32; off; off >>= 1) {
        np  += __shfl_down(np, off, 64);
        cnt += __shfl_down(cnt, off, 64);
    }
    float num = 0.f;
    if (lane == 0) {
        int l0 = lab[b * S_];
        int ll = lab[b * S_ + cnt - 1];
        size_t i0 = (size_t)b * S_ * NL_ + l0;
        num = np + start_t[l0] + em_f[i0] + em_b[i0] + b_out[l0] + end_t[ll];
    }

    // ---- denominator ----
    const int j = (lane < NL_) ? lane : (NL_ - 1);
    const float boj = b_out[j];
    float Tc[NL_];
#pragma unroll
    for (int i = 0; i < NL_; i++) Tc[i] = trans[i * NL_ + j];
    const size_t base = (size_t)b * S_ * NL_;
    float sc = start_t[j] + em_f[base + j] + em_b[base + j] + boj;
    float nf = em_f[base + NL_ + j];
    float nbv = em_b[base + NL_ + j];
    int nm = seq[b * S_ + 1];
    for (int t = 1; t < S_; t++) {
        float emv = nf + nbv + boj;
        int msk = nm;
        if (t < S_ - 1) {                      // prefetch t+1
            size_t ix2 = base + (size_t)(t + 1) * NL_ + j;
            nf  = em_f[ix2];
            nbv = em_b[ix2];
            nm  = seq[b * S_ + t + 1];
        }
        float a[NL_];
#pragma unroll
        for (int i = 0; i < NL_; i++) a[i] = __shfl(sc, i, 64) + Tc[i];
        float m = a[0];
#pragma unroll
        for (int i = 1; i < NL_; i++) m = fmaxf(m, a[i]);
        float sum = 0.f;
#pragma unroll
        for (int i = 0; i < NL_; i++) sum += exp2f((a[i] - m) * L2E);
        float nxt = emv + m + LN2 * log2f(sum);
        sc = msk ? nxt : sc;
    }
    float v = sc + end_t[j];
    float mm = -1e30f, av[NL_];
#pragma unroll
    for (int i = 0; i < NL_; i++) { float vi = __shfl(v, i, 64); av[i] = vi; mm = fmaxf(mm, vi); }
    float ss = 0.f;
#pragma unroll
    for (int i = 0; i < NL_; i++) ss += exp2f((av[i] - mm) * L2E);
    if (lane == 0) partial[b] = (mm + LN2 * log2f(ss)) - num;
}

__global__ __launch_bounds__(128)
void reduce_kernel(const float* __restrict__ partial, float* __restrict__ out)
{
    __shared__ float s[128];
    int tid = threadIdx.x;
    s[tid] = partial[tid];
    __syncthreads();
    for (int off = 64; off; off >>= 1) {
        if (tid < off) s[tid] += s[tid + off];
        __syncthreads();
    }
    if (tid == 0) out[0] = s[0];
}

extern "C" void kernel_launch(void* const* d_in, const int* in_sizes, int n_in,
                              void* d_out, int out_size, void* d_ws, size_t ws_size,
                              hipStream_t stream)
{
    const int* seq = (const int*)d_in[0];
    const int* lab = (const int*)d_in[1];
    const float* emb    = (const float*)d_in[2];
    const float* w_ih_f = (const float*)d_in[3];
    const float* w_hh_f = (const float*)d_in[4];
    const float* b_ih_f = (const float*)d_in[5];
    const float* b_hh_f = (const float*)d_in[6];
    const float* w_ih_b = (const float*)d_in[7];
    const float* w_hh_b = (const float*)d_in[8];
    const float* b_ih_b = (const float*)d_in[9];
    const float* b_hh_b = (const float*)d_in[10];
    const float* w_out  = (const float*)d_in[11];
    const float* b_out  = (const float*)d_in[12];
    const float* start_t = (const float*)d_in[13];
    const float* end_t   = (const float*)d_in[14];
    const float* trans   = (const float*)d_in[15];

    char* ws = (char*)d_ws;
    const size_t em_bytes = (size_t)B_ * S_ * NL_ * sizeof(float);
    float* em_f    = (float*)ws;
    float* em_b    = (float*)(ws + em_bytes);
    float* partial = (float*)(ws + 2 * em_bytes);

    lstm_em_kernel<<<dim3(128), dim3(512), 0, stream>>>(seq, emb,
        w_ih_f, w_hh_f, b_ih_f, b_hh_f, w_ih_b, w_hh_b, b_ih_b, b_hh_b,
        w_out, em_f, em_b);
    crf_kernel<<<dim3(B_), dim3(64), 0, stream>>>(seq, lab, em_f, em_b, b_out,
        start_t, end_t, trans, partial);
    reduce_kernel<<<dim3(1), dim3(128), 0, stream>>>(partial, (float*)d_out);
}